// Round 4
// baseline (1043.286 us; speedup 1.0000x reference)
//
#include <hip/hip_runtime.h>
#include <stdint.h>

// Problem constants
#define NB 2
#define NS 2048
#define NE 1024
#define NH 16
#define ND 64

typedef __attribute__((ext_vector_type(8))) short short8;
typedef __attribute__((ext_vector_type(4))) float f4;
typedef __attribute__((ext_vector_type(4))) unsigned short us4;

static __device__ __forceinline__ unsigned short bf16_rne(float x) {
  uint32_t u = __builtin_bit_cast(uint32_t, x);
  u += 0x7fffu + ((u >> 16) & 1u);
  return (unsigned short)(u >> 16);
}
static __device__ __forceinline__ float bf16_f32(unsigned short h) {
  uint32_t u = ((uint32_t)h) << 16;
  return __builtin_bit_cast(float, u);
}

// JAX threefry2x32, key = (0, 42), 20 rounds.
static __device__ __forceinline__ void threefry42(uint32_t x0, uint32_t x1,
                                                  uint32_t& o0, uint32_t& o1) {
  const uint32_t ks0 = 0u, ks1 = 42u;
  const uint32_t ks2 = 0u ^ 42u ^ 0x1BD11BDAu;
  x0 += ks0; x1 += ks1;
#define TF4(a,b,c,d) \
  x0 += x1; x1 = __builtin_rotateleft32(x1, a); x1 ^= x0; \
  x0 += x1; x1 = __builtin_rotateleft32(x1, b); x1 ^= x0; \
  x0 += x1; x1 = __builtin_rotateleft32(x1, c); x1 ^= x0; \
  x0 += x1; x1 = __builtin_rotateleft32(x1, d); x1 ^= x0;
  TF4(13,15,26,6)  x0 += ks1; x1 += ks2 + 1u;
  TF4(17,29,16,24) x0 += ks2; x1 += ks0 + 2u;
  TF4(13,15,26,6)  x0 += ks0; x1 += ks1 + 3u;
  TF4(17,29,16,24) x0 += ks1; x1 += ks2 + 4u;
  TF4(13,15,26,6)  x0 += ks2; x1 += ks0 + 5u;
#undef TF4
  o0 = x0; o1 = x1;
}

// async global->LDS 16B/lane.
static __device__ __forceinline__ void gl2lds16(const void* g, void* l) {
  __builtin_amdgcn_global_load_lds(
      (const __attribute__((address_space(1))) uint32_t*)g,
      (__attribute__((address_space(3))) uint32_t*)l, 16, 0, 0);
}

// ---------------- kernel 0: split fp32 -> bf16 hi/lo ----------------
__global__ void k_split(const float* __restrict__ x, const float* __restrict__ qw,
                        const float* __restrict__ ow,
                        unsigned short* __restrict__ xh, unsigned short* __restrict__ xl,
                        unsigned short* __restrict__ wh, unsigned short* __restrict__ wl,
                        unsigned short* __restrict__ woh) {
  for (uint32_t i = blockIdx.x * 256u + threadIdx.x; i < 8388608u; i += gridDim.x * 256u) {
    if (i < 4194304u) {
      float v = x[i];
      unsigned short hi = bf16_rne(v);
      xh[i] = hi;
      xl[i] = bf16_rne(v - bf16_f32(hi));
    } else if (i < 7340032u) {
      uint32_t j = i - 4194304u;
      float v = qw[j];
      unsigned short hi = bf16_rne(v);
      wh[j] = hi;
      wl[j] = bf16_rne(v - bf16_f32(hi));
    } else {
      uint32_t j = i - 7340032u;
      woh[j] = bf16_rne(ow[j]);
    }
  }
}

// ---------------- kernel 1: QKV GEMM, split-bf16 MFMA ----------------
__global__ __launch_bounds__(256) void k_qkv(
    const unsigned short* __restrict__ xh, const unsigned short* __restrict__ xl,
    const unsigned short* __restrict__ wh, const unsigned short* __restrict__ wl,
    const float* __restrict__ qkv_b,
    float* __restrict__ Qf, float* __restrict__ Kf, unsigned short* __restrict__ Vh) {
  __shared__ unsigned short Ah[128 * 32], Al[128 * 32], Bh[128 * 32], Bl[128 * 32];
  const int tid = threadIdx.x;
  const int lane = tid & 63, wid = tid >> 6;
  const int wm = wid >> 1, wn = wid & 1;
  const int bn = blockIdx.x, bm = blockIdx.y;
  const int quad = lane >> 4, c16 = lane & 15;
  const int ldrow = lane >> 2;
  const int ldk = (lane & 3) * 8;

  f4 acc[4][4];
#pragma unroll
  for (int a = 0; a < 4; ++a)
#pragma unroll
    for (int b = 0; b < 4; ++b) { f4 z = {0.f, 0.f, 0.f, 0.f}; acc[a][b] = z; }

  for (int kt = 0; kt < 32; ++kt) {
    const int k0 = kt * 32;
    __syncthreads();
#pragma unroll
    for (int r = 0; r < 2; ++r) {
      const int c = wid + r * 4;
      const int grow = c * 16 + ldrow;
      const size_t ao = (size_t)(bm * 128 + grow) * 1024 + k0 + ldk;
      const size_t bo = (size_t)(bn * 128 + grow) * 1024 + k0 + ldk;
      const int lo = c * 512 + lane * 8;
      gl2lds16(xh + ao, &Ah[lo]);
      gl2lds16(xl + ao, &Al[lo]);
      gl2lds16(wh + bo, &Bh[lo]);
      gl2lds16(wl + bo, &Bl[lo]);
    }
    __syncthreads();

    short8 ah[4], al[4], bh[4], bl[4];
#pragma unroll
    for (int t = 0; t < 4; ++t) {
      ah[t] = *(const short8*)&Ah[(wm * 64 + t * 16 + c16) * 32 + quad * 8];
      al[t] = *(const short8*)&Al[(wm * 64 + t * 16 + c16) * 32 + quad * 8];
      bh[t] = *(const short8*)&Bh[(wn * 64 + t * 16 + c16) * 32 + quad * 8];
      bl[t] = *(const short8*)&Bl[(wn * 64 + t * 16 + c16) * 32 + quad * 8];
    }
#pragma unroll
    for (int tm = 0; tm < 4; ++tm)
#pragma unroll
      for (int tn = 0; tn < 4; ++tn) {
        acc[tm][tn] = __builtin_amdgcn_mfma_f32_16x16x32_bf16(ah[tm], bh[tn], acc[tm][tn], 0, 0, 0);
        acc[tm][tn] = __builtin_amdgcn_mfma_f32_16x16x32_bf16(ah[tm], bl[tn], acc[tm][tn], 0, 0, 0);
        acc[tm][tn] = __builtin_amdgcn_mfma_f32_16x16x32_bf16(al[tm], bh[tn], acc[tm][tn], 0, 0, 0);
      }
  }

  // epilogue: C/D layout col=lane&15, row=quad*4+reg
#pragma unroll
  for (int tm = 0; tm < 4; ++tm) {
#pragma unroll
    for (int tn = 0; tn < 4; ++tn) {
      const int j = bn * 128 + wn * 64 + tn * 16 + c16;
      const float bias = qkv_b[j];
      const int which = j >> 10;
      const int rem = j & 1023;
      const int h = rem >> 6, d = rem & 63;
#pragma unroll
      for (int r = 0; r < 4; ++r) {
        const int i = bm * 128 + wm * 64 + tm * 16 + quad * 4 + r;
        const int b = i >> 11, s = i & 2047;
        const size_t off = (((size_t)(b * 16 + h)) * 2048 + (size_t)s) * 64 + d;
        const float v = acc[tm][tn][r] + bias;
        if (which == 0) Qf[off] = v;
        else if (which == 1) Kf[off] = v;
        else Vh[off] = bf16_rne(v);
      }
    }
  }
}

// ---------------- kernel 2: attention with exact threefry sampling ----------------
// RNG (round 4): JAX partitionable stream, f32 draws. Per flat element f of
// [B,H,S,S]: (o0,o1) = threefry2x32(key=(0,42), x0=hi32(f)=0, x1=f);
// 32-bit bits = o0 ^ o1 (JAX folds the two output words for bit_width<=32);
// u = bitcast((bits>>9)|0x3f800000)-1; sample = u < p (strict).
__global__ __launch_bounds__(256) void k_attn(
    const float* __restrict__ Qf, const float* __restrict__ Kf,
    const unsigned short* __restrict__ Vh, unsigned short* __restrict__ AO) {
  __shared__ float Qs[64][68];     // +4 pad: bank-conflict-free f4 reads
  __shared__ float KVs[64][68];    // K tile, then V tile
  __shared__ uint32_t Ms[64 * 17]; // sample bytes [64][68]
  const int tid = threadIdx.x;
  const int tk = tid & 15;  // phase A: k-lane; phase B: d-lane
  const int tq = tid >> 4;  // q-group 0..15 (4 rows each)
  const int h = blockIdx.y;
  const int q0 = blockIdx.x * 64;

  for (int b = 0; b < 2; ++b) {
    const size_t bh = (size_t)(b * 16 + h) * (size_t)(2048 * 64);
    const float* Qb = Qf + bh;
    const float* Kb = Kf + bh;
    const unsigned short* Vb = Vh + bh;
    const uint32_t fbase = (uint32_t)(b * 16 + h) * (2048u * 2048u);

    __syncthreads();
    for (int it = tid; it < 1024; it += 256) {   // Q tile 64x64 f32
      const int r = it >> 4, c = it & 15;
      *(f4*)&Qs[r][c * 4] = *(const f4*)&Qb[(size_t)(q0 + r) * 64 + c * 4];
    }

    f4 acc[4];
#pragma unroll
    for (int qi = 0; qi < 4; ++qi) { f4 z = {0.f, 0.f, 0.f, 0.f}; acc[qi] = z; }

    for (int kt = 0; kt < 32; ++kt) {
      const int kb = kt * 64;
      __syncthreads();
      for (int it = tid; it < 1024; it += 256) { // K tile 64x64 f32
        const int r = it >> 4, c = it & 15;
        *(f4*)&KVs[r][c * 4] = *(const f4*)&Kb[(size_t)(kb + r) * 64 + c * 4];
      }
      __syncthreads();

      // phase A: scores (fp32), thread tile 4q x 4k (k = tk + 16*ki)
      float sc[4][4] = {{0.f}};
#pragma unroll
      for (int dc = 0; dc < 16; ++dc) {
        f4 qv[4], kv[4];
#pragma unroll
        for (int qi = 0; qi < 4; ++qi) qv[qi] = *(const f4*)&Qs[tq * 4 + qi][dc * 4];
#pragma unroll
        for (int ki = 0; ki < 4; ++ki) kv[ki] = *(const f4*)&KVs[tk + 16 * ki][dc * 4];
#pragma unroll
        for (int qi = 0; qi < 4; ++qi)
#pragma unroll
          for (int ki = 0; ki < 4; ++ki) {
            float s = sc[qi][ki];
            s = fmaf(qv[qi][0], kv[ki][0], s);
            s = fmaf(qv[qi][1], kv[ki][1], s);
            s = fmaf(qv[qi][2], kv[ki][2], s);
            s = fmaf(qv[qi][3], kv[ki][3], s);
            sc[qi][ki] = s;
          }
      }
      // RNG + sigmoid + sample -> byte mask
      unsigned char* Mb = (unsigned char*)Ms;
#pragma unroll
      for (int qi = 0; qi < 4; ++qi) {
        const uint32_t qg = (uint32_t)(q0 + tq * 4 + qi);
#pragma unroll
        for (int ki = 0; ki < 4; ++ki) {
          const uint32_t kg = (uint32_t)(kb + tk + 16 * ki);
          const uint32_t f = fbase + qg * 2048u + kg;
          uint32_t o0, o1;
          threefry42(0u, f, o0, o1);
          const uint32_t bits = o0 ^ o1;
          const float u = __builtin_bit_cast(float, (bits >> 9) | 0x3f800000u) - 1.0f;
          const float p = 1.0f / (1.0f + __expf(sc[qi][ki] * -0.125f));
          Mb[(tq * 4 + qi) * 68 + (tk + 16 * ki)] = (u < p) ? 1 : 0;
        }
      }
      __syncthreads();
      for (int it = tid; it < 1024; it += 256) { // V tile bf16 -> f32 into KVs
        const int r = it >> 4, c = it & 15;
        us4 vv = *(const us4*)&Vb[(size_t)(kb + r) * 64 + c * 4];
        float* dst = &KVs[r][c * 4];
        dst[0] = bf16_f32(vv[0]); dst[1] = bf16_f32(vv[1]);
        dst[2] = bf16_f32(vv[2]); dst[3] = bf16_f32(vv[3]);
      }
      __syncthreads();

      // phase B: masked accumulate, thread tile 4q x 4d (d = tk*4..+3)
#pragma unroll
      for (int g = 0; g < 16; ++g) {
        uint32_t mw[4];
#pragma unroll
        for (int qi = 0; qi < 4; ++qi) mw[qi] = Ms[(tq * 4 + qi) * 17 + g];
        f4 vv[4];
#pragma unroll
        for (int j = 0; j < 4; ++j) vv[j] = *(const f4*)&KVs[g * 4 + j][tk * 4];
#pragma unroll
        for (int qi = 0; qi < 4; ++qi)
#pragma unroll
          for (int j = 0; j < 4; ++j) {
            const float m = (float)((mw[qi] >> (8 * j)) & 0xffu);
            acc[qi] += vv[j] * m;
          }
      }
    }

    // epilogue: AO[b][s][h*64+d] bf16
#pragma unroll
    for (int qi = 0; qi < 4; ++qi) {
      const int s = q0 + tq * 4 + qi;
      us4 o;
      o[0] = bf16_rne(acc[qi][0]); o[1] = bf16_rne(acc[qi][1]);
      o[2] = bf16_rne(acc[qi][2]); o[3] = bf16_rne(acc[qi][3]);
      *(us4*)&AO[((size_t)b * 2048 + s) * 1024 + h * 64 + tk * 4] = o;
    }
  }
}

// ---------------- kernel 3: output projection, bf16 MFMA ----------------
__global__ __launch_bounds__(256) void k_out(
    const unsigned short* __restrict__ A, const unsigned short* __restrict__ Bw,
    const float* __restrict__ out_b, float* __restrict__ out) {
  __shared__ unsigned short As[128 * 32], Bs[128 * 32];
  const int tid = threadIdx.x;
  const int lane = tid & 63, wid = tid >> 6;
  const int wm = wid >> 1, wn = wid & 1;
  const int bn = blockIdx.x, bm = blockIdx.y;
  const int quad = lane >> 4, c16 = lane & 15;
  const int ldrow = lane >> 2;
  const int ldk = (lane & 3) * 8;

  f4 acc[4][4];
#pragma unroll
  for (int a = 0; a < 4; ++a)
#pragma unroll
    for (int b = 0; b < 4; ++b) { f4 z = {0.f, 0.f, 0.f, 0.f}; acc[a][b] = z; }

  for (int kt = 0; kt < 32; ++kt) {
    const int k0 = kt * 32;
    __syncthreads();
#pragma unroll
    for (int r = 0; r < 2; ++r) {
      const int c = wid + r * 4;
      const int grow = c * 16 + ldrow;
      const size_t ao = (size_t)(bm * 128 + grow) * 1024 + k0 + ldk;
      const size_t bo = (size_t)(bn * 128 + grow) * 1024 + k0 + ldk;
      const int lo = c * 512 + lane * 8;
      gl2lds16(A + ao, &As[lo]);
      gl2lds16(Bw + bo, &Bs[lo]);
    }
    __syncthreads();

    short8 af[4], bf[4];
#pragma unroll
    for (int t = 0; t < 4; ++t) {
      af[t] = *(const short8*)&As[(wm * 64 + t * 16 + c16) * 32 + quad * 8];
      bf[t] = *(const short8*)&Bs[(wn * 64 + t * 16 + c16) * 32 + quad * 8];
    }
#pragma unroll
    for (int tm = 0; tm < 4; ++tm)
#pragma unroll
      for (int tn = 0; tn < 4; ++tn)
        acc[tm][tn] = __builtin_amdgcn_mfma_f32_16x16x32_bf16(af[tm], bf[tn], acc[tm][tn], 0, 0, 0);
  }

#pragma unroll
  for (int tm = 0; tm < 4; ++tm) {
#pragma unroll
    for (int tn = 0; tn < 4; ++tn) {
      const int j = bn * 128 + wn * 64 + tn * 16 + c16;
      const float bias = out_b[j];
#pragma unroll
      for (int r = 0; r < 4; ++r) {
        const int i = bm * 128 + wm * 64 + tm * 16 + quad * 4 + r;
        out[(size_t)i * 1024 + j] = acc[tm][tn][r] + bias;
      }
    }
  }
}

extern "C" void kernel_launch(void* const* d_in, const int* in_sizes, int n_in,
                              void* d_out, int out_size, void* d_ws, size_t ws_size,
                              hipStream_t stream) {
  const float* x     = (const float*)d_in[0];
  const float* qkv_w = (const float*)d_in[3];
  const float* qkv_b = (const float*)d_in[4];
  const float* out_w = (const float*)d_in[5];
  const float* out_b = (const float*)d_in[6];
  float* out = (float*)d_out;

  unsigned short* xh  = (unsigned short*)d_ws;        // 4194304
  unsigned short* xl  = xh + 4194304;                 // 4194304
  unsigned short* wh  = xl + 4194304;                 // 3145728
  unsigned short* wl  = wh + 3145728;                 // 3145728
  unsigned short* woh = wl + 3145728;                 // 1048576
  unsigned short* Vh  = woh + 1048576;                // 4194304
  unsigned short* AO  = Vh + 4194304;                 // 4194304
  float* Qf = (float*)(AO + 4194304);                 // 4194304 f32
  float* Kf = Qf + 4194304;                           // 4194304 f32

  k_split<<<8192, 256, 0, stream>>>(x, qkv_w, out_w, xh, xl, wh, wl, woh);
  k_qkv<<<dim3(24, 32), 256, 0, stream>>>(xh, xl, wh, wl, qkv_b, Qf, Kf, Vh);
  k_attn<<<dim3(32, 16), 256, 0, stream>>>(Qf, Kf, Vh, AO);
  k_out<<<dim3(8, 32), 256, 0, stream>>>(AO, woh, out_b, out);
}

// Round 5
// 532.730 us; speedup vs baseline: 1.9584x; 1.9584x over previous
//
#include <hip/hip_runtime.h>
#include <stdint.h>

// Problem constants
#define NB 2
#define NS 2048
#define NE 1024
#define NH 16
#define ND 64

typedef __attribute__((ext_vector_type(8))) short short8;
typedef __attribute__((ext_vector_type(4))) float f4;
typedef __attribute__((ext_vector_type(4))) unsigned short us4;

static __device__ __forceinline__ unsigned short bf16_rne(float x) {
  uint32_t u = __builtin_bit_cast(uint32_t, x);
  u += 0x7fffu + ((u >> 16) & 1u);
  return (unsigned short)(u >> 16);
}
static __device__ __forceinline__ float bf16_f32(unsigned short h) {
  uint32_t u = ((uint32_t)h) << 16;
  return __builtin_bit_cast(float, u);
}

// JAX threefry2x32, key = (0, 42), 20 rounds.
static __device__ __forceinline__ void threefry42(uint32_t x0, uint32_t x1,
                                                  uint32_t& o0, uint32_t& o1) {
  const uint32_t ks0 = 0u, ks1 = 42u;
  const uint32_t ks2 = 0u ^ 42u ^ 0x1BD11BDAu;
  x0 += ks0; x1 += ks1;
#define TF4(a,b,c,d) \
  x0 += x1; x1 = __builtin_rotateleft32(x1, a); x1 ^= x0; \
  x0 += x1; x1 = __builtin_rotateleft32(x1, b); x1 ^= x0; \
  x0 += x1; x1 = __builtin_rotateleft32(x1, c); x1 ^= x0; \
  x0 += x1; x1 = __builtin_rotateleft32(x1, d); x1 ^= x0;
  TF4(13,15,26,6)  x0 += ks1; x1 += ks2 + 1u;
  TF4(17,29,16,24) x0 += ks2; x1 += ks0 + 2u;
  TF4(13,15,26,6)  x0 += ks0; x1 += ks1 + 3u;
  TF4(17,29,16,24) x0 += ks1; x1 += ks2 + 4u;
  TF4(13,15,26,6)  x0 += ks2; x1 += ks0 + 5u;
#undef TF4
  o0 = x0; o1 = x1;
}

// async global->LDS 16B/lane.
static __device__ __forceinline__ void gl2lds16(const void* g, void* l) {
  __builtin_amdgcn_global_load_lds(
      (const __attribute__((address_space(1))) uint32_t*)g,
      (__attribute__((address_space(3))) uint32_t*)l, 16, 0, 0);
}

// ---------------- kernel 0: split fp32 -> bf16 hi/lo ----------------
__global__ void k_split(const float* __restrict__ x, const float* __restrict__ qw,
                        const float* __restrict__ ow,
                        unsigned short* __restrict__ xh, unsigned short* __restrict__ xl,
                        unsigned short* __restrict__ wh, unsigned short* __restrict__ wl,
                        unsigned short* __restrict__ woh) {
  for (uint32_t i = blockIdx.x * 256u + threadIdx.x; i < 8388608u; i += gridDim.x * 256u) {
    if (i < 4194304u) {
      float v = x[i];
      unsigned short hi = bf16_rne(v);
      xh[i] = hi;
      xl[i] = bf16_rne(v - bf16_f32(hi));
    } else if (i < 7340032u) {
      uint32_t j = i - 4194304u;
      float v = qw[j];
      unsigned short hi = bf16_rne(v);
      wh[j] = hi;
      wl[j] = bf16_rne(v - bf16_f32(hi));
    } else {
      uint32_t j = i - 7340032u;
      woh[j] = bf16_rne(ow[j]);
    }
  }
}

// ---------------- kernel 1: QKV GEMM, split-bf16 MFMA ----------------
// C[4096][3072] = X @ W^T. Epilogue: Q,K -> bf16 hi/lo [bh][s][d];
// V -> bf16 transposed Vt[bh][d][s] (so PV's B-operand is row-contiguous in k).
__global__ __launch_bounds__(256) void k_qkv(
    const unsigned short* __restrict__ xh, const unsigned short* __restrict__ xl,
    const unsigned short* __restrict__ wh, const unsigned short* __restrict__ wl,
    const float* __restrict__ qkv_b,
    unsigned short* __restrict__ Qh, unsigned short* __restrict__ Ql,
    unsigned short* __restrict__ Kh, unsigned short* __restrict__ Kl,
    unsigned short* __restrict__ Vt) {
  __shared__ unsigned short Ah[128 * 32], Al[128 * 32], Bh[128 * 32], Bl[128 * 32];
  const int tid = threadIdx.x;
  const int lane = tid & 63, wid = tid >> 6;
  const int wm = wid >> 1, wn = wid & 1;
  const int bn = blockIdx.x, bm = blockIdx.y;
  const int quad = lane >> 4, c16 = lane & 15;
  const int ldrow = lane >> 2;
  const int ldk = (lane & 3) * 8;

  f4 acc[4][4];
#pragma unroll
  for (int a = 0; a < 4; ++a)
#pragma unroll
    for (int b = 0; b < 4; ++b) { f4 z = {0.f, 0.f, 0.f, 0.f}; acc[a][b] = z; }

  for (int kt = 0; kt < 32; ++kt) {
    const int k0 = kt * 32;
    __syncthreads();
#pragma unroll
    for (int r = 0; r < 2; ++r) {
      const int c = wid + r * 4;
      const int grow = c * 16 + ldrow;
      const size_t ao = (size_t)(bm * 128 + grow) * 1024 + k0 + ldk;
      const size_t bo = (size_t)(bn * 128 + grow) * 1024 + k0 + ldk;
      const int lo = c * 512 + lane * 8;
      gl2lds16(xh + ao, &Ah[lo]);
      gl2lds16(xl + ao, &Al[lo]);
      gl2lds16(wh + bo, &Bh[lo]);
      gl2lds16(wl + bo, &Bl[lo]);
    }
    __syncthreads();

    short8 ah[4], al[4], bhf[4], blf[4];
#pragma unroll
    for (int t = 0; t < 4; ++t) {
      ah[t] = *(const short8*)&Ah[(wm * 64 + t * 16 + c16) * 32 + quad * 8];
      al[t] = *(const short8*)&Al[(wm * 64 + t * 16 + c16) * 32 + quad * 8];
      bhf[t] = *(const short8*)&Bh[(wn * 64 + t * 16 + c16) * 32 + quad * 8];
      blf[t] = *(const short8*)&Bl[(wn * 64 + t * 16 + c16) * 32 + quad * 8];
    }
#pragma unroll
    for (int tm = 0; tm < 4; ++tm)
#pragma unroll
      for (int tn = 0; tn < 4; ++tn) {
        acc[tm][tn] = __builtin_amdgcn_mfma_f32_16x16x32_bf16(ah[tm], bhf[tn], acc[tm][tn], 0, 0, 0);
        acc[tm][tn] = __builtin_amdgcn_mfma_f32_16x16x32_bf16(ah[tm], blf[tn], acc[tm][tn], 0, 0, 0);
        acc[tm][tn] = __builtin_amdgcn_mfma_f32_16x16x32_bf16(al[tm], bhf[tn], acc[tm][tn], 0, 0, 0);
      }
  }

  // epilogue: C/D layout col=lane&15, row=quad*4+reg
#pragma unroll
  for (int tm = 0; tm < 4; ++tm) {
#pragma unroll
    for (int tn = 0; tn < 4; ++tn) {
      const int j = bn * 128 + wn * 64 + tn * 16 + c16;
      const float bias = qkv_b[j];
      const int which = j >> 10;
      const int rem = j & 1023;
      const int h = rem >> 6, d = rem & 63;
#pragma unroll
      for (int r = 0; r < 4; ++r) {
        const int i = bm * 128 + wm * 64 + tm * 16 + quad * 4 + r;
        const int b = i >> 11, s = i & 2047;
        const int bh = b * 16 + h;
        const float v = acc[tm][tn][r] + bias;
        if (which == 2) {
          Vt[((size_t)bh * 64 + d) * 2048 + s] = bf16_rne(v);
        } else {
          const size_t off = ((size_t)bh * 2048 + s) * 64 + d;
          const unsigned short hi = bf16_rne(v);
          const unsigned short lo = bf16_rne(v - bf16_f32(hi));
          if (which == 0) { Qh[off] = hi; Ql[off] = lo; }
          else            { Kh[off] = hi; Kl[off] = lo; }
        }
      }
    }
  }
}

// ---------------- kernel 2: MFMA flash attention + exact threefry sampling ----
// Block = 64-q-tile of one (b,h); 4 waves, each owns 16 q rows.
// Per 64-k-tile: stage Kh/Kl/Vt via global_load_lds; S = Q.K^T (split-bf16,
// 3 passes, 6 MFMA/subtile); threefry+sigmoid -> 0/1 bf16 mask in LDS (wave-
// private rows, no barrier); O += P.V (exact, 8 MFMA). Threefry is the floor.
__global__ __launch_bounds__(256) void k_attn(
    const unsigned short* __restrict__ Qh, const unsigned short* __restrict__ Ql,
    const unsigned short* __restrict__ Khg, const unsigned short* __restrict__ Klg,
    const unsigned short* __restrict__ Vtg, unsigned short* __restrict__ AO) {
  __shared__ unsigned short Ksh[4096], Ksl[4096], Vs[4096], Pm[4096];
  const int tid = threadIdx.x;
  const int lane = tid & 63, w = tid >> 6;
  const int quad = lane >> 4, c16 = lane & 15;
  const int q0 = blockIdx.x * 64;
  const int bh = blockIdx.y;
  const size_t base = (size_t)bh * (size_t)(2048 * 64);

  // Q fragments for this wave's 16 rows (A-operand: m=c16, k=quad*8+j)
  const size_t qoff = base + (size_t)(q0 + w * 16 + c16) * 64 + quad * 8;
  const short8 qh0 = *(const short8*)&Qh[qoff];
  const short8 qh1 = *(const short8*)&Qh[qoff + 32];
  const short8 ql0 = *(const short8*)&Ql[qoff];
  const short8 ql1 = *(const short8*)&Ql[qoff + 32];

  // flat-index base for threefry: f = bh*2^22 + q*2048 + k
  const uint32_t fb = (uint32_t)bh * 4194304u +
                      (uint32_t)(q0 + w * 16 + quad * 4) * 2048u + (uint32_t)c16;

  f4 oacc[4];
#pragma unroll
  for (int s = 0; s < 4; ++s) { f4 z = {0.f, 0.f, 0.f, 0.f}; oacc[s] = z; }

  for (int kt = 0; kt < 32; ++kt) {
    const int kb = kt * 64;
    const size_t koff = base + (size_t)kb * 64;
    __syncthreads();
#pragma unroll
    for (int rd = 0; rd < 2; ++rd) {
      const int lo = rd * 2048 + tid * 8;           // K tiles are contiguous 8KB
      gl2lds16(Khg + koff + lo, &Ksh[lo]);
      gl2lds16(Klg + koff + lo, &Ksl[lo]);
      const int cid = rd * 256 + tid;               // Vt tile: 64 rows, stride 2048
      const int vr = cid >> 3, vc = (cid & 7) * 8;
      gl2lds16(Vtg + base + (size_t)vr * 2048 + kb + vc, &Vs[cid * 8]);
    }
    __syncthreads();

    // S = Q.K^T, per wave 16q x 64k (4 subtiles along k), split-bf16 3 passes
    f4 sacc[4];
#pragma unroll
    for (int sub = 0; sub < 4; ++sub) {
      const int br = (sub * 16 + c16) * 64 + quad * 8;
      const short8 kh0 = *(const short8*)&Ksh[br];
      const short8 kh1 = *(const short8*)&Ksh[br + 32];
      const short8 kl0 = *(const short8*)&Ksl[br];
      const short8 kl1 = *(const short8*)&Ksl[br + 32];
      f4 s = {0.f, 0.f, 0.f, 0.f};
      s = __builtin_amdgcn_mfma_f32_16x16x32_bf16(qh0, kh0, s, 0, 0, 0);
      s = __builtin_amdgcn_mfma_f32_16x16x32_bf16(qh1, kh1, s, 0, 0, 0);
      s = __builtin_amdgcn_mfma_f32_16x16x32_bf16(qh0, kl0, s, 0, 0, 0);
      s = __builtin_amdgcn_mfma_f32_16x16x32_bf16(qh1, kl1, s, 0, 0, 0);
      s = __builtin_amdgcn_mfma_f32_16x16x32_bf16(ql0, kh0, s, 0, 0, 0);
      s = __builtin_amdgcn_mfma_f32_16x16x32_bf16(ql1, kh1, s, 0, 0, 0);
      sacc[sub] = s;
    }

    // sample: u < p  <=>  (float)(bits>>9) < p * 2^23   (exact transform)
#pragma unroll
    for (int sub = 0; sub < 4; ++sub) {
#pragma unroll
      for (int r = 0; r < 4; ++r) {
        const uint32_t f = fb + (uint32_t)(r * 2048) + (uint32_t)(kb + sub * 16);
        uint32_t o0, o1;
        threefry42(0u, f, o0, o1);
        const float m = (float)((o0 ^ o1) >> 9);
        const float e = __expf(sacc[sub][r] * -0.125f);
        const float p23 = 8388608.0f * __builtin_amdgcn_rcpf(1.0f + e);
        Pm[(w * 16 + quad * 4 + r) * 64 + sub * 16 + c16] = (m < p23) ? 0x3F80u : 0u;
      }
    }

    // O += P.V  — P rows are wave-private; compiler's lgkmcnt orders write->read
    const int pr = (w * 16 + c16) * 64 + quad * 8;
    const short8 pa0 = *(const short8*)&Pm[pr];
    const short8 pa1 = *(const short8*)&Pm[pr + 32];
#pragma unroll
    for (int sub = 0; sub < 4; ++sub) {
      const int vr = (sub * 16 + c16) * 64 + quad * 8;
      const short8 vb0 = *(const short8*)&Vs[vr];
      const short8 vb1 = *(const short8*)&Vs[vr + 32];
      oacc[sub] = __builtin_amdgcn_mfma_f32_16x16x32_bf16(pa0, vb0, oacc[sub], 0, 0, 0);
      oacc[sub] = __builtin_amdgcn_mfma_f32_16x16x32_bf16(pa1, vb1, oacc[sub], 0, 0, 0);
    }
  }

  // epilogue: AO[b*2048+s][h*64+d] bf16; C-layout row=quad*4+r (q), col=c16 (d)
  const int b = bh >> 4, hh = bh & 15;
#pragma unroll
  for (int sub = 0; sub < 4; ++sub)
#pragma unroll
    for (int r = 0; r < 4; ++r) {
      const int srow = b * 2048 + q0 + w * 16 + quad * 4 + r;
      AO[(size_t)srow * 1024 + hh * 64 + sub * 16 + c16] = bf16_rne(oacc[sub][r]);
    }
}

// ---------------- kernel 3: output projection, bf16 MFMA ----------------
__global__ __launch_bounds__(256) void k_out(
    const unsigned short* __restrict__ A, const unsigned short* __restrict__ Bw,
    const float* __restrict__ out_b, float* __restrict__ out) {
  __shared__ unsigned short As[128 * 32], Bs[128 * 32];
  const int tid = threadIdx.x;
  const int lane = tid & 63, wid = tid >> 6;
  const int wm = wid >> 1, wn = wid & 1;
  const int bn = blockIdx.x, bm = blockIdx.y;
  const int quad = lane >> 4, c16 = lane & 15;
  const int ldrow = lane >> 2;
  const int ldk = (lane & 3) * 8;

  f4 acc[4][4];
#pragma unroll
  for (int a = 0; a < 4; ++a)
#pragma unroll
    for (int b = 0; b < 4; ++b) { f4 z = {0.f, 0.f, 0.f, 0.f}; acc[a][b] = z; }

  for (int kt = 0; kt < 32; ++kt) {
    const int k0 = kt * 32;
    __syncthreads();
#pragma unroll
    for (int r = 0; r < 2; ++r) {
      const int c = wid + r * 4;
      const int grow = c * 16 + ldrow;
      const size_t ao = (size_t)(bm * 128 + grow) * 1024 + k0 + ldk;
      const size_t bo = (size_t)(bn * 128 + grow) * 1024 + k0 + ldk;
      const int lo = c * 512 + lane * 8;
      gl2lds16(A + ao, &As[lo]);
      gl2lds16(Bw + bo, &Bs[lo]);
    }
    __syncthreads();

    short8 af[4], bf[4];
#pragma unroll
    for (int t = 0; t < 4; ++t) {
      af[t] = *(const short8*)&As[(wm * 64 + t * 16 + c16) * 32 + quad * 8];
      bf[t] = *(const short8*)&Bs[(wn * 64 + t * 16 + c16) * 32 + quad * 8];
    }
#pragma unroll
    for (int tm = 0; tm < 4; ++tm)
#pragma unroll
      for (int tn = 0; tn < 4; ++tn)
        acc[tm][tn] = __builtin_amdgcn_mfma_f32_16x16x32_bf16(af[tm], bf[tn], acc[tm][tn], 0, 0, 0);
  }

#pragma unroll
  for (int tm = 0; tm < 4; ++tm) {
#pragma unroll
    for (int tn = 0; tn < 4; ++tn) {
      const int j = bn * 128 + wn * 64 + tn * 16 + c16;
      const float bias = out_b[j];
#pragma unroll
      for (int r = 0; r < 4; ++r) {
        const int i = bm * 128 + wm * 64 + tm * 16 + quad * 4 + r;
        out[(size_t)i * 1024 + j] = acc[tm][tn][r] + bias;
      }
    }
  }
}

extern "C" void kernel_launch(void* const* d_in, const int* in_sizes, int n_in,
                              void* d_out, int out_size, void* d_ws, size_t ws_size,
                              hipStream_t stream) {
  const float* x     = (const float*)d_in[0];
  const float* qkv_w = (const float*)d_in[3];
  const float* qkv_b = (const float*)d_in[4];
  const float* out_w = (const float*)d_in[5];
  const float* out_b = (const float*)d_in[6];
  float* out = (float*)d_out;

  // workspace carve (ushorts); AO aliases xh (xh dead after k_qkv)
  unsigned short* xh  = (unsigned short*)d_ws;        // 4194304
  unsigned short* xl  = xh + 4194304;                 // 4194304
  unsigned short* wh  = xl + 4194304;                 // 3145728
  unsigned short* wl  = wh + 3145728;                 // 3145728
  unsigned short* woh = wl + 3145728;                 // 1048576
  unsigned short* Vt  = woh + 1048576;                // 4194304
  unsigned short* Qh  = Vt + 4194304;                 // 4194304
  unsigned short* Ql  = Qh + 4194304;                 // 4194304
  unsigned short* Kh  = Ql + 4194304;                 // 4194304
  unsigned short* Kl  = Kh + 4194304;                 // 4194304
  unsigned short* AO  = xh;                           // alias

  k_split<<<8192, 256, 0, stream>>>(x, qkv_w, out_w, xh, xl, wh, wl, woh);
  k_qkv<<<dim3(24, 32), 256, 0, stream>>>(xh, xl, wh, wl, qkv_b, Qh, Ql, Kh, Kl, Vt);
  k_attn<<<dim3(32, 32), 256, 0, stream>>>(Qh, Ql, Kh, Kl, Vt, AO);
  k_out<<<dim3(8, 32), 256, 0, stream>>>(AO, woh, out_b, out);
}

// Round 7
// 520.157 us; speedup vs baseline: 2.0057x; 1.0242x over previous
//
#include <hip/hip_runtime.h>
#include <stdint.h>

// Problem constants
#define NB 2
#define NS 2048
#define NE 1024
#define NH 16
#define ND 64

typedef __attribute__((ext_vector_type(8))) short short8;
typedef __attribute__((ext_vector_type(4))) float f4;
typedef __attribute__((ext_vector_type(4))) unsigned short us4;

static __device__ __forceinline__ unsigned short bf16_rne(float x) {
  uint32_t u = __builtin_bit_cast(uint32_t, x);
  u += 0x7fffu + ((u >> 16) & 1u);
  return (unsigned short)(u >> 16);
}
static __device__ __forceinline__ float bf16_f32(unsigned short h) {
  uint32_t u = ((uint32_t)h) << 16;
  return __builtin_bit_cast(float, u);
}

// JAX threefry2x32, key = (0, 42), 20 rounds.
static __device__ __forceinline__ void threefry42(uint32_t x0, uint32_t x1,
                                                  uint32_t& o0, uint32_t& o1) {
  const uint32_t ks0 = 0u, ks1 = 42u;
  const uint32_t ks2 = 0u ^ 42u ^ 0x1BD11BDAu;
  x0 += ks0; x1 += ks1;
#define TF4(a,b,c,d) \
  x0 += x1; x1 = __builtin_rotateleft32(x1, a); x1 ^= x0; \
  x0 += x1; x1 = __builtin_rotateleft32(x1, b); x1 ^= x0; \
  x0 += x1; x1 = __builtin_rotateleft32(x1, c); x1 ^= x0; \
  x0 += x1; x1 = __builtin_rotateleft32(x1, d); x1 ^= x0;
  TF4(13,15,26,6)  x0 += ks1; x1 += ks2 + 1u;
  TF4(17,29,16,24) x0 += ks2; x1 += ks0 + 2u;
  TF4(13,15,26,6)  x0 += ks0; x1 += ks1 + 3u;
  TF4(17,29,16,24) x0 += ks1; x1 += ks2 + 4u;
  TF4(13,15,26,6)  x0 += ks2; x1 += ks0 + 5u;
#undef TF4
  o0 = x0; o1 = x1;
}

// async global->LDS 16B/lane.
static __device__ __forceinline__ void gl2lds16(const void* g, void* l) {
  __builtin_amdgcn_global_load_lds(
      (const __attribute__((address_space(1))) uint32_t*)g,
      (__attribute__((address_space(3))) uint32_t*)l, 16, 0, 0);
}

// ---------------- kernel 0: split fp32 -> bf16 hi/lo ----------------
__global__ void k_split(const float* __restrict__ x, const float* __restrict__ qw,
                        const float* __restrict__ ow,
                        unsigned short* __restrict__ xh, unsigned short* __restrict__ xl,
                        unsigned short* __restrict__ wh, unsigned short* __restrict__ wl,
                        unsigned short* __restrict__ woh) {
  for (uint32_t i = blockIdx.x * 256u + threadIdx.x; i < 8388608u; i += gridDim.x * 256u) {
    if (i < 4194304u) {
      float v = x[i];
      unsigned short hi = bf16_rne(v);
      xh[i] = hi;
      xl[i] = bf16_rne(v - bf16_f32(hi));
    } else if (i < 7340032u) {
      uint32_t j = i - 4194304u;
      float v = qw[j];
      unsigned short hi = bf16_rne(v);
      wh[j] = hi;
      wl[j] = bf16_rne(v - bf16_f32(hi));
    } else {
      uint32_t j = i - 7340032u;
      woh[j] = bf16_rne(ow[j]);
    }
  }
}

// ---------------- kernel 1: QKV GEMM, split-bf16 MFMA ----------------
// Q,K blocks (bn<16): 3-pass split-bf16, hi/lo outputs.
// V blocks (bn>=16): 1-pass bf16, epilogue LDS-transpose -> coalesced Vt stores.
__global__ __launch_bounds__(256) void k_qkv(
    const unsigned short* __restrict__ xh, const unsigned short* __restrict__ xl,
    const unsigned short* __restrict__ wh, const unsigned short* __restrict__ wl,
    const float* __restrict__ qkv_b,
    unsigned short* __restrict__ Qh, unsigned short* __restrict__ Ql,
    unsigned short* __restrict__ Kh, unsigned short* __restrict__ Kl,
    unsigned short* __restrict__ Vt) {
  __shared__ unsigned short SM[16384];  // 32KB, carved; reused by V transpose
  unsigned short* Ah = SM;
  unsigned short* Al = SM + 4096;
  unsigned short* Bh = SM + 8192;
  unsigned short* Bl = SM + 12288;
  const int tid = threadIdx.x;
  const int lane = tid & 63, wid = tid >> 6;
  const int wm = wid >> 1, wn = wid & 1;
  const int bn = blockIdx.x, bm = blockIdx.y;
  const bool isV = (bn >= 16);
  const int quad = lane >> 4, c16 = lane & 15;
  const int ldrow = lane >> 2;
  const int ldk = (lane & 3) * 8;

  f4 acc[4][4];
#pragma unroll
  for (int a = 0; a < 4; ++a)
#pragma unroll
    for (int b = 0; b < 4; ++b) { f4 z = {0.f, 0.f, 0.f, 0.f}; acc[a][b] = z; }

  for (int kt = 0; kt < 32; ++kt) {
    const int k0 = kt * 32;
    __syncthreads();
#pragma unroll
    for (int r = 0; r < 2; ++r) {
      const int c = wid + r * 4;
      const int grow = c * 16 + ldrow;
      const size_t ao = (size_t)(bm * 128 + grow) * 1024 + k0 + ldk;
      const size_t bo = (size_t)(bn * 128 + grow) * 1024 + k0 + ldk;
      const int lo = c * 512 + lane * 8;
      gl2lds16(xh + ao, &Ah[lo]);
      gl2lds16(wh + bo, &Bh[lo]);
      if (!isV) {
        gl2lds16(xl + ao, &Al[lo]);
        gl2lds16(wl + bo, &Bl[lo]);
      }
    }
    __syncthreads();

    short8 ah[4], al[4], bhf[4], blf[4];
#pragma unroll
    for (int t = 0; t < 4; ++t) {
      ah[t] = *(const short8*)&Ah[(wm * 64 + t * 16 + c16) * 32 + quad * 8];
      bhf[t] = *(const short8*)&Bh[(wn * 64 + t * 16 + c16) * 32 + quad * 8];
      if (!isV) {
        al[t] = *(const short8*)&Al[(wm * 64 + t * 16 + c16) * 32 + quad * 8];
        blf[t] = *(const short8*)&Bl[(wn * 64 + t * 16 + c16) * 32 + quad * 8];
      }
    }
    if (isV) {
#pragma unroll
      for (int tm = 0; tm < 4; ++tm)
#pragma unroll
        for (int tn = 0; tn < 4; ++tn)
          acc[tm][tn] = __builtin_amdgcn_mfma_f32_16x16x32_bf16(ah[tm], bhf[tn], acc[tm][tn], 0, 0, 0);
    } else {
#pragma unroll
      for (int tm = 0; tm < 4; ++tm)
#pragma unroll
        for (int tn = 0; tn < 4; ++tn) {
          acc[tm][tn] = __builtin_amdgcn_mfma_f32_16x16x32_bf16(ah[tm], bhf[tn], acc[tm][tn], 0, 0, 0);
          acc[tm][tn] = __builtin_amdgcn_mfma_f32_16x16x32_bf16(ah[tm], blf[tn], acc[tm][tn], 0, 0, 0);
          acc[tm][tn] = __builtin_amdgcn_mfma_f32_16x16x32_bf16(al[tm], bhf[tn], acc[tm][tn], 0, 0, 0);
        }
    }
  }

  if (!isV) {
    // epilogue Q/K: hi/lo bf16 [bh][s][d]
#pragma unroll
    for (int tm = 0; tm < 4; ++tm) {
#pragma unroll
      for (int tn = 0; tn < 4; ++tn) {
        const int j = bn * 128 + wn * 64 + tn * 16 + c16;
        const float bias = qkv_b[j];
        const int which = j >> 10;
        const int rem = j & 1023;
        const int h = rem >> 6, d = rem & 63;
#pragma unroll
        for (int r = 0; r < 4; ++r) {
          const int i = bm * 128 + wm * 64 + tm * 16 + quad * 4 + r;
          const int b = i >> 11, s = i & 2047;
          const size_t off = (((size_t)(b * 16 + h)) * 2048 + (size_t)s) * 64 + d;
          const float v = acc[tm][tn][r] + bias;
          const unsigned short hi = bf16_rne(v);
          const unsigned short lo = bf16_rne(v - bf16_f32(hi));
          if (which == 0) { Qh[off] = hi; Ql[off] = lo; }
          else            { Kh[off] = hi; Kl[off] = lo; }
        }
      }
    }
  } else {
    // epilogue V: LDS transpose [d_local 128][s_local 128], then coalesced Vt
    __syncthreads();
#pragma unroll
    for (int tm = 0; tm < 4; ++tm) {
#pragma unroll
      for (int tn = 0; tn < 4; ++tn) {
        const int j = bn * 128 + wn * 64 + tn * 16 + c16;
        const float bias = qkv_b[j];
        const int d_local = wn * 64 + tn * 16 + c16;
#pragma unroll
        for (int r = 0; r < 4; ++r) {
          const int s_local = wm * 64 + tm * 16 + quad * 4 + r;
          SM[d_local * 128 + s_local] = bf16_rne(acc[tm][tn][r] + bias);
        }
      }
    }
    __syncthreads();
    const int b = (bm * 128) >> 11;
    const int s0 = (bm * 128) & 2047;   // FIX: per-batch s offset (bm*128 is global row)
    const int h2 = (bn - 16) * 2;
#pragma unroll
    for (int it = 0; it < 8; ++it) {
      const int chunk = it * 256 + tid;     // 2048 chunks of 8 ushorts
      const int dr = chunk >> 4;            // 0..127
      const int sc = (chunk & 15) * 8;
      const short8 v = *(const short8*)&SM[dr * 128 + sc];
      const int bh = b * 16 + h2 + (dr >> 6);
      const int d = dr & 63;
      *(short8*)&Vt[((size_t)bh * 64 + d) * 2048 + s0 + sc] = v;
    }
  }
}

// ---------------- kernel 2: MFMA flash attention + exact threefry sampling ----
// Pipelined single-buffer staging + swizzled LDS (row-rotated 16B chunks) to
// kill bank conflicts. Per 64-k-tile: frag reads -> barrier -> issue next-tile
// global_load_lds -> long compute (QK MFMA, threefry, PV MFMA) with loads in
// flight -> loop-top barrier (vmcnt already drained).
__global__ __launch_bounds__(256) void k_attn(
    const unsigned short* __restrict__ Qh, const unsigned short* __restrict__ Ql,
    const unsigned short* __restrict__ Khg, const unsigned short* __restrict__ Klg,
    const unsigned short* __restrict__ Vtg, unsigned short* __restrict__ AO) {
  __shared__ unsigned short Ksh[4096], Ksl[4096], Vs[4096], Pm[4096];
  const int tid = threadIdx.x;
  const int lane = tid & 63, w = tid >> 6;
  const int quad = lane >> 4, c16 = lane & 15;
  const int q0 = blockIdx.x * 64;
  const int bh = blockIdx.y;
  const size_t base = (size_t)bh * (size_t)(2048 * 64);

  // Q fragments for this wave's 16 rows (A-operand: m=c16, k=quad*8+j)
  const size_t qoff = base + (size_t)(q0 + w * 16 + c16) * 64 + quad * 8;
  const short8 qh0 = *(const short8*)&Qh[qoff];
  const short8 qh1 = *(const short8*)&Qh[qoff + 32];
  const short8 ql0 = *(const short8*)&Ql[qoff];
  const short8 ql1 = *(const short8*)&Ql[qoff + 32];

  // flat-index base for threefry: f = bh*2^22 + q*2048 + k
  const uint32_t fb = (uint32_t)bh * 4194304u +
                      (uint32_t)(q0 + w * 16 + quad * 4) * 2048u + (uint32_t)c16;

  // swizzled staging indices: LDS chunk c holds global chunk ((c&7) - (c>>3)) & 7
  const int c0 = tid, r0 = c0 >> 3, g0 = ((c0 & 7) - r0) & 7;
  const int c1 = tid + 256, r1 = c1 >> 3, g1 = ((c1 & 7) - r1) & 7;

  f4 oacc[4];
#pragma unroll
  for (int s = 0; s < 4; ++s) { f4 z = {0.f, 0.f, 0.f, 0.f}; oacc[s] = z; }

  auto stage = [&](int kb) {
    const size_t koff = base + (size_t)kb * 64;
    gl2lds16(Khg + koff + r0 * 64 + g0 * 8, &Ksh[c0 * 8]);
    gl2lds16(Klg + koff + r0 * 64 + g0 * 8, &Ksl[c0 * 8]);
    gl2lds16(Vtg + base + (size_t)r0 * 2048 + kb + g0 * 8, &Vs[c0 * 8]);
    gl2lds16(Khg + koff + r1 * 64 + g1 * 8, &Ksh[c1 * 8]);
    gl2lds16(Klg + koff + r1 * 64 + g1 * 8, &Ksl[c1 * 8]);
    gl2lds16(Vtg + base + (size_t)r1 * 2048 + kb + g1 * 8, &Vs[c1 * 8]);
  };

  stage(0);

  for (int kt = 0; kt < 32; ++kt) {
    const int kb = kt * 64;
    __syncthreads();  // tile kb staged (own vmcnt long-drained) + all waves past prev compute

    // fragment reads (swizzled rows): K hi/lo + V, all to regs
    short8 kh[8], kl[8], vv[8];
#pragma unroll
    for (int sub = 0; sub < 4; ++sub) {
      const int rK = sub * 16 + c16;
      const int sA = ((quad + rK) & 7) * 8;
      const int sB = ((quad + 4 + rK) & 7) * 8;
      kh[2 * sub] = *(const short8*)&Ksh[rK * 64 + sA];
      kh[2 * sub + 1] = *(const short8*)&Ksh[rK * 64 + sB];
      kl[2 * sub] = *(const short8*)&Ksl[rK * 64 + sA];
      kl[2 * sub + 1] = *(const short8*)&Ksl[rK * 64 + sB];
      vv[2 * sub] = *(const short8*)&Vs[rK * 64 + sA];
      vv[2 * sub + 1] = *(const short8*)&Vs[rK * 64 + sB];
    }
    __syncthreads();  // all waves done reading K/V tiles
    if (kt < 31) stage(kb + 64);  // overwrite; lands during long compute below

    // S = Q.K^T split-bf16 3 passes (6 MFMA per 16x16 subtile)
    f4 sacc[4];
#pragma unroll
    for (int sub = 0; sub < 4; ++sub) {
      f4 s = {0.f, 0.f, 0.f, 0.f};
      s = __builtin_amdgcn_mfma_f32_16x16x32_bf16(qh0, kh[2 * sub], s, 0, 0, 0);
      s = __builtin_amdgcn_mfma_f32_16x16x32_bf16(qh1, kh[2 * sub + 1], s, 0, 0, 0);
      s = __builtin_amdgcn_mfma_f32_16x16x32_bf16(qh0, kl[2 * sub], s, 0, 0, 0);
      s = __builtin_amdgcn_mfma_f32_16x16x32_bf16(qh1, kl[2 * sub + 1], s, 0, 0, 0);
      s = __builtin_amdgcn_mfma_f32_16x16x32_bf16(ql0, kh[2 * sub], s, 0, 0, 0);
      s = __builtin_amdgcn_mfma_f32_16x16x32_bf16(ql1, kh[2 * sub + 1], s, 0, 0, 0);
      sacc[sub] = s;
    }

    // threefry + sigmoid sample -> swizzled Pm (0x3F80 / 0 bf16 mask)
    // u < p  <=>  m*(1+e) < 2^23  with m = (float)((o0^o1)>>9), e = exp(-s/8)
#pragma unroll
    for (int sub = 0; sub < 4; ++sub) {
      const int qP = sub * 2 + (c16 >> 3);
#pragma unroll
      for (int rr = 0; rr < 4; ++rr) {
        const uint32_t f = fb + (uint32_t)(rr * 2048) + (uint32_t)(kb + sub * 16);
        uint32_t o0, o1;
        threefry42(0u, f, o0, o1);
        const float m = (float)((o0 ^ o1) >> 9);
        const float e = __expf(sacc[sub][rr] * -0.125f);
        const int rP = w * 16 + quad * 4 + rr;
        const int addr = rP * 64 + (((qP + rP) & 7) * 8) + (c16 & 7);
        Pm[addr] = (fmaf(m, e, m) < 8388608.0f) ? 0x3F80u : 0u;
      }
    }

    // O += P.V (P rows wave-private; lgkmcnt orders write->read)
    const int rp = w * 16 + c16;
    const short8 pa0 = *(const short8*)&Pm[rp * 64 + ((quad + rp) & 7) * 8];
    const short8 pa1 = *(const short8*)&Pm[rp * 64 + ((quad + 4 + rp) & 7) * 8];
#pragma unroll
    for (int sub = 0; sub < 4; ++sub) {
      oacc[sub] = __builtin_amdgcn_mfma_f32_16x16x32_bf16(pa0, vv[2 * sub], oacc[sub], 0, 0, 0);
      oacc[sub] = __builtin_amdgcn_mfma_f32_16x16x32_bf16(pa1, vv[2 * sub + 1], oacc[sub], 0, 0, 0);
    }
  }

  // epilogue: AO[b*2048+s][h*64+d] bf16; C-layout row=quad*4+r (q), col=c16 (d)
  const int b = bh >> 4, hh = bh & 15;
#pragma unroll
  for (int sub = 0; sub < 4; ++sub)
#pragma unroll
    for (int r = 0; r < 4; ++r) {
      const int srow = b * 2048 + q0 + w * 16 + quad * 4 + r;
      AO[(size_t)srow * 1024 + hh * 64 + sub * 16 + c16] = bf16_rne(oacc[sub][r]);
    }
}

// ---------------- kernel 3: output projection, bf16 MFMA ----------------
__global__ __launch_bounds__(256) void k_out(
    const unsigned short* __restrict__ A, const unsigned short* __restrict__ Bw,
    const float* __restrict__ out_b, float* __restrict__ out) {
  __shared__ unsigned short As[128 * 32], Bs[128 * 32];
  const int tid = threadIdx.x;
  const int lane = tid & 63, wid = tid >> 6;
  const int wm = wid >> 1, wn = wid & 1;
  const int bn = blockIdx.x, bm = blockIdx.y;
  const int quad = lane >> 4, c16 = lane & 15;
  const int ldrow = lane >> 2;
  const int ldk = (lane & 3) * 8;

  f4 acc[4][4];
#pragma unroll
  for (int a = 0; a < 4; ++a)
#pragma unroll
    for (int b = 0; b < 4; ++b) { f4 z = {0.f, 0.f, 0.f, 0.f}; acc[a][b] = z; }

  for (int kt = 0; kt < 32; ++kt) {
    const int k0 = kt * 32;
    __syncthreads();
#pragma unroll
    for (int r = 0; r < 2; ++r) {
      const int c = wid + r * 4;
      const int grow = c * 16 + ldrow;
      const size_t ao = (size_t)(bm * 128 + grow) * 1024 + k0 + ldk;
      const size_t bo = (size_t)(bn * 128 + grow) * 1024 + k0 + ldk;
      const int lo = c * 512 + lane * 8;
      gl2lds16(A + ao, &As[lo]);
      gl2lds16(Bw + bo, &Bs[lo]);
    }
    __syncthreads();

    short8 af[4], bf[4];
#pragma unroll
    for (int t = 0; t < 4; ++t) {
      af[t] = *(const short8*)&As[(wm * 64 + t * 16 + c16) * 32 + quad * 8];
      bf[t] = *(const short8*)&Bs[(wn * 64 + t * 16 + c16) * 32 + quad * 8];
    }
#pragma unroll
    for (int tm = 0; tm < 4; ++tm)
#pragma unroll
      for (int tn = 0; tn < 4; ++tn)
        acc[tm][tn] = __builtin_amdgcn_mfma_f32_16x16x32_bf16(af[tm], bf[tn], acc[tm][tn], 0, 0, 0);
  }

#pragma unroll
  for (int tm = 0; tm < 4; ++tm) {
#pragma unroll
    for (int tn = 0; tn < 4; ++tn) {
      const int j = bn * 128 + wn * 64 + tn * 16 + c16;
      const float bias = out_b[j];
#pragma unroll
      for (int r = 0; r < 4; ++r) {
        const int i = bm * 128 + wm * 64 + tm * 16 + quad * 4 + r;
        out[(size_t)i * 1024 + j] = acc[tm][tn][r] + bias;
      }
    }
  }
}

extern "C" void kernel_launch(void* const* d_in, const int* in_sizes, int n_in,
                              void* d_out, int out_size, void* d_ws, size_t ws_size,
                              hipStream_t stream) {
  const float* x     = (const float*)d_in[0];
  const float* qkv_w = (const float*)d_in[3];
  const float* qkv_b = (const float*)d_in[4];
  const float* out_w = (const float*)d_in[5];
  const float* out_b = (const float*)d_in[6];
  float* out = (float*)d_out;

  // workspace carve (ushorts); AO aliases xh (xh dead after k_qkv)
  unsigned short* xh  = (unsigned short*)d_ws;        // 4194304
  unsigned short* xl  = xh + 4194304;                 // 4194304
  unsigned short* wh  = xl + 4194304;                 // 3145728
  unsigned short* wl  = wh + 3145728;                 // 3145728
  unsigned short* woh = wl + 3145728;                 // 1048576
  unsigned short* Vt  = woh + 1048576;                // 4194304
  unsigned short* Qh  = Vt + 4194304;                 // 4194304
  unsigned short* Ql  = Qh + 4194304;                 // 4194304
  unsigned short* Kh  = Ql + 4194304;                 // 4194304
  unsigned short* Kl  = Kh + 4194304;                 // 4194304
  unsigned short* AO  = xh;                           // alias

  k_split<<<8192, 256, 0, stream>>>(x, qkv_w, out_w, xh, xl, wh, wl, woh);
  k_qkv<<<dim3(24, 32), 256, 0, stream>>>(xh, xl, wh, wl, qkv_b, Qh, Ql, Kh, Kl, Vt);
  k_attn<<<dim3(32, 32), 256, 0, stream>>>(Qh, Ql, Kh, Kl, Vt, AO);
  k_out<<<dim3(8, 32), 256, 0, stream>>>(AO, woh, out_b, out);
}

// Round 8
// 507.966 us; speedup vs baseline: 2.0539x; 1.0240x over previous
//
#include <hip/hip_runtime.h>
#include <stdint.h>

// Problem constants
#define NB 2
#define NS 2048
#define NE 1024
#define NH 16
#define ND 64

typedef __attribute__((ext_vector_type(8))) short short8;
typedef __attribute__((ext_vector_type(4))) float f4;
typedef __attribute__((ext_vector_type(4))) unsigned short us4;

static __device__ __forceinline__ unsigned short bf16_rne(float x) {
  uint32_t u = __builtin_bit_cast(uint32_t, x);
  u += 0x7fffu + ((u >> 16) & 1u);
  return (unsigned short)(u >> 16);
}
static __device__ __forceinline__ float bf16_f32(unsigned short h) {
  uint32_t u = ((uint32_t)h) << 16;
  return __builtin_bit_cast(float, u);
}

// JAX threefry2x32, key = (0, 42), 20 rounds.
static __device__ __forceinline__ void threefry42(uint32_t x0, uint32_t x1,
                                                  uint32_t& o0, uint32_t& o1) {
  const uint32_t ks0 = 0u, ks1 = 42u;
  const uint32_t ks2 = 0u ^ 42u ^ 0x1BD11BDAu;
  x0 += ks0; x1 += ks1;
#define TF4(a,b,c,d) \
  x0 += x1; x1 = __builtin_rotateleft32(x1, a); x1 ^= x0; \
  x0 += x1; x1 = __builtin_rotateleft32(x1, b); x1 ^= x0; \
  x0 += x1; x1 = __builtin_rotateleft32(x1, c); x1 ^= x0; \
  x0 += x1; x1 = __builtin_rotateleft32(x1, d); x1 ^= x0;
  TF4(13,15,26,6)  x0 += ks1; x1 += ks2 + 1u;
  TF4(17,29,16,24) x0 += ks2; x1 += ks0 + 2u;
  TF4(13,15,26,6)  x0 += ks0; x1 += ks1 + 3u;
  TF4(17,29,16,24) x0 += ks1; x1 += ks2 + 4u;
  TF4(13,15,26,6)  x0 += ks2; x1 += ks0 + 5u;
#undef TF4
  o0 = x0; o1 = x1;
}

// async global->LDS 16B/lane.
static __device__ __forceinline__ void gl2lds16(const void* g, void* l) {
  __builtin_amdgcn_global_load_lds(
      (const __attribute__((address_space(1))) uint32_t*)g,
      (__attribute__((address_space(3))) uint32_t*)l, 16, 0, 0);
}

// ---------------- kernel 0: split fp32 -> bf16 hi/lo ----------------
__global__ void k_split(const float* __restrict__ x, const float* __restrict__ qw,
                        const float* __restrict__ ow,
                        unsigned short* __restrict__ xh, unsigned short* __restrict__ xl,
                        unsigned short* __restrict__ wh, unsigned short* __restrict__ wl,
                        unsigned short* __restrict__ woh) {
  for (uint32_t i = blockIdx.x * 256u + threadIdx.x; i < 8388608u; i += gridDim.x * 256u) {
    if (i < 4194304u) {
      float v = x[i];
      unsigned short hi = bf16_rne(v);
      xh[i] = hi;
      xl[i] = bf16_rne(v - bf16_f32(hi));
    } else if (i < 7340032u) {
      uint32_t j = i - 4194304u;
      float v = qw[j];
      unsigned short hi = bf16_rne(v);
      wh[j] = hi;
      wl[j] = bf16_rne(v - bf16_f32(hi));
    } else {
      uint32_t j = i - 7340032u;
      woh[j] = bf16_rne(ow[j]);
    }
  }
}

// ---------------- kernel 1: QKV GEMM, split-bf16 MFMA ----------------
// Q,K blocks (bn<16): 3-pass split-bf16, hi/lo outputs.
// V blocks (bn>=16): 1-pass bf16, epilogue LDS-transpose -> coalesced Vt stores.
__global__ __launch_bounds__(256) void k_qkv(
    const unsigned short* __restrict__ xh, const unsigned short* __restrict__ xl,
    const unsigned short* __restrict__ wh, const unsigned short* __restrict__ wl,
    const float* __restrict__ qkv_b,
    unsigned short* __restrict__ Qh, unsigned short* __restrict__ Ql,
    unsigned short* __restrict__ Kh, unsigned short* __restrict__ Kl,
    unsigned short* __restrict__ Vt) {
  __shared__ unsigned short SM[16384];  // 32KB, carved; reused by V transpose
  unsigned short* Ah = SM;
  unsigned short* Al = SM + 4096;
  unsigned short* Bh = SM + 8192;
  unsigned short* Bl = SM + 12288;
  const int tid = threadIdx.x;
  const int lane = tid & 63, wid = tid >> 6;
  const int wm = wid >> 1, wn = wid & 1;
  const int bn = blockIdx.x, bm = blockIdx.y;
  const bool isV = (bn >= 16);
  const int quad = lane >> 4, c16 = lane & 15;
  const int ldrow = lane >> 2;
  const int ldk = (lane & 3) * 8;

  f4 acc[4][4];
#pragma unroll
  for (int a = 0; a < 4; ++a)
#pragma unroll
    for (int b = 0; b < 4; ++b) { f4 z = {0.f, 0.f, 0.f, 0.f}; acc[a][b] = z; }

  for (int kt = 0; kt < 32; ++kt) {
    const int k0 = kt * 32;
    __syncthreads();
#pragma unroll
    for (int r = 0; r < 2; ++r) {
      const int c = wid + r * 4;
      const int grow = c * 16 + ldrow;
      const size_t ao = (size_t)(bm * 128 + grow) * 1024 + k0 + ldk;
      const size_t bo = (size_t)(bn * 128 + grow) * 1024 + k0 + ldk;
      const int lo = c * 512 + lane * 8;
      gl2lds16(xh + ao, &Ah[lo]);
      gl2lds16(wh + bo, &Bh[lo]);
      if (!isV) {
        gl2lds16(xl + ao, &Al[lo]);
        gl2lds16(wl + bo, &Bl[lo]);
      }
    }
    __syncthreads();

    short8 ah[4], al[4], bhf[4], blf[4];
#pragma unroll
    for (int t = 0; t < 4; ++t) {
      ah[t] = *(const short8*)&Ah[(wm * 64 + t * 16 + c16) * 32 + quad * 8];
      bhf[t] = *(const short8*)&Bh[(wn * 64 + t * 16 + c16) * 32 + quad * 8];
      if (!isV) {
        al[t] = *(const short8*)&Al[(wm * 64 + t * 16 + c16) * 32 + quad * 8];
        blf[t] = *(const short8*)&Bl[(wn * 64 + t * 16 + c16) * 32 + quad * 8];
      }
    }
    if (isV) {
#pragma unroll
      for (int tm = 0; tm < 4; ++tm)
#pragma unroll
        for (int tn = 0; tn < 4; ++tn)
          acc[tm][tn] = __builtin_amdgcn_mfma_f32_16x16x32_bf16(ah[tm], bhf[tn], acc[tm][tn], 0, 0, 0);
    } else {
#pragma unroll
      for (int tm = 0; tm < 4; ++tm)
#pragma unroll
        for (int tn = 0; tn < 4; ++tn) {
          acc[tm][tn] = __builtin_amdgcn_mfma_f32_16x16x32_bf16(ah[tm], bhf[tn], acc[tm][tn], 0, 0, 0);
          acc[tm][tn] = __builtin_amdgcn_mfma_f32_16x16x32_bf16(ah[tm], blf[tn], acc[tm][tn], 0, 0, 0);
          acc[tm][tn] = __builtin_amdgcn_mfma_f32_16x16x32_bf16(al[tm], bhf[tn], acc[tm][tn], 0, 0, 0);
        }
    }
  }

  if (!isV) {
    // epilogue Q/K: hi/lo bf16 [bh][s][d]
#pragma unroll
    for (int tm = 0; tm < 4; ++tm) {
#pragma unroll
      for (int tn = 0; tn < 4; ++tn) {
        const int j = bn * 128 + wn * 64 + tn * 16 + c16;
        const float bias = qkv_b[j];
        const int which = j >> 10;
        const int rem = j & 1023;
        const int h = rem >> 6, d = rem & 63;
#pragma unroll
        for (int r = 0; r < 4; ++r) {
          const int i = bm * 128 + wm * 64 + tm * 16 + quad * 4 + r;
          const int b = i >> 11, s = i & 2047;
          const size_t off = (((size_t)(b * 16 + h)) * 2048 + (size_t)s) * 64 + d;
          const float v = acc[tm][tn][r] + bias;
          const unsigned short hi = bf16_rne(v);
          const unsigned short lo = bf16_rne(v - bf16_f32(hi));
          if (which == 0) { Qh[off] = hi; Ql[off] = lo; }
          else            { Kh[off] = hi; Kl[off] = lo; }
        }
      }
    }
  } else {
    // epilogue V: LDS transpose [d_local 128][s_local 128], then coalesced Vt
    __syncthreads();
#pragma unroll
    for (int tm = 0; tm < 4; ++tm) {
#pragma unroll
      for (int tn = 0; tn < 4; ++tn) {
        const int j = bn * 128 + wn * 64 + tn * 16 + c16;
        const float bias = qkv_b[j];
        const int d_local = wn * 64 + tn * 16 + c16;
#pragma unroll
        for (int r = 0; r < 4; ++r) {
          const int s_local = wm * 64 + tm * 16 + quad * 4 + r;
          SM[d_local * 128 + s_local] = bf16_rne(acc[tm][tn][r] + bias);
        }
      }
    }
    __syncthreads();
    const int b = (bm * 128) >> 11;
    const int s0 = (bm * 128) & 2047;   // per-batch s offset (bm*128 is global row)
    const int h2 = (bn - 16) * 2;
#pragma unroll
    for (int it = 0; it < 8; ++it) {
      const int chunk = it * 256 + tid;     // 2048 chunks of 8 ushorts
      const int dr = chunk >> 4;            // 0..127
      const int sc = (chunk & 15) * 8;
      const short8 v = *(const short8*)&SM[dr * 128 + sc];
      const int bh = b * 16 + h2 + (dr >> 6);
      const int d = dr & 63;
      *(short8*)&Vt[((size_t)bh * 64 + d) * 2048 + s0 + sc] = v;
    }
  }
}

// ---------------- kernel 2: MFMA flash attention + exact threefry sampling ----
// Swizzled LDS (row-rotated 16B chunks, 0 bank conflicts) + pipelined staging.
// This round: low-VGPR variant — K fragments read inline during S-compute
// (consumed before barrier-2); V double-buffered in LDS so PV reads inline
// after barrier-2 while staging fills the other V buffer. Live-across-barrier
// register state ~48 (sacc+Qfrags+oacc) vs round-7's 144.
__global__ __launch_bounds__(256) void k_attn(
    const unsigned short* __restrict__ Qh, const unsigned short* __restrict__ Ql,
    const unsigned short* __restrict__ Khg, const unsigned short* __restrict__ Klg,
    const unsigned short* __restrict__ Vtg, unsigned short* __restrict__ AO) {
  __shared__ unsigned short Ksh[4096], Ksl[4096], Vs[8192], Pm[4096];
  const int tid = threadIdx.x;
  const int lane = tid & 63, w = tid >> 6;
  const int quad = lane >> 4, c16 = lane & 15;
  const int q0 = blockIdx.x * 64;
  const int bh = blockIdx.y;
  const size_t base = (size_t)bh * (size_t)(2048 * 64);

  // Q fragments for this wave's 16 rows (A-operand: m=c16, k=quad*8+j)
  const size_t qoff = base + (size_t)(q0 + w * 16 + c16) * 64 + quad * 8;
  const short8 qh0 = *(const short8*)&Qh[qoff];
  const short8 qh1 = *(const short8*)&Qh[qoff + 32];
  const short8 ql0 = *(const short8*)&Ql[qoff];
  const short8 ql1 = *(const short8*)&Ql[qoff + 32];

  // flat-index base for threefry: f = bh*2^22 + q*2048 + k
  const uint32_t fb = (uint32_t)bh * 4194304u +
                      (uint32_t)(q0 + w * 16 + quad * 4) * 2048u + (uint32_t)c16;

  // swizzled staging indices: LDS chunk c holds global chunk ((c&7) - (c>>3)) & 7
  const int c0 = tid, r0 = c0 >> 3, g0 = ((c0 & 7) - r0) & 7;
  const int c1 = tid + 256, r1 = c1 >> 3, g1 = ((c1 & 7) - r1) & 7;

  f4 oacc[4];
#pragma unroll
  for (int s = 0; s < 4; ++s) { f4 z = {0.f, 0.f, 0.f, 0.f}; oacc[s] = z; }

  auto stage = [&](int kb, int vbuf) {
    const size_t koff = base + (size_t)kb * 64;
    gl2lds16(Khg + koff + r0 * 64 + g0 * 8, &Ksh[c0 * 8]);
    gl2lds16(Klg + koff + r0 * 64 + g0 * 8, &Ksl[c0 * 8]);
    gl2lds16(Vtg + base + (size_t)r0 * 2048 + kb + g0 * 8, &Vs[vbuf * 4096 + c0 * 8]);
    gl2lds16(Khg + koff + r1 * 64 + g1 * 8, &Ksh[c1 * 8]);
    gl2lds16(Klg + koff + r1 * 64 + g1 * 8, &Ksl[c1 * 8]);
    gl2lds16(Vtg + base + (size_t)r1 * 2048 + kb + g1 * 8, &Vs[vbuf * 4096 + c1 * 8]);
  };

  stage(0, 0);

  for (int kt = 0; kt < 32; ++kt) {
    const int kb = kt * 64;
    const int vb = (kt & 1) * 4096;
    __syncthreads();  // tile kb staged; all waves past previous compute

    // S = Q.K^T split-bf16 3 passes; K fragments read inline (swizzled rows)
    f4 sacc[4];
#pragma unroll
    for (int sub = 0; sub < 4; ++sub) {
      const int rK = sub * 16 + c16;
      const int sA = ((quad + rK) & 7) * 8;
      const int sB = ((quad + 4 + rK) & 7) * 8;
      const short8 kh0 = *(const short8*)&Ksh[rK * 64 + sA];
      const short8 kh1 = *(const short8*)&Ksh[rK * 64 + sB];
      const short8 kl0 = *(const short8*)&Ksl[rK * 64 + sA];
      const short8 kl1 = *(const short8*)&Ksl[rK * 64 + sB];
      f4 s = {0.f, 0.f, 0.f, 0.f};
      s = __builtin_amdgcn_mfma_f32_16x16x32_bf16(qh0, kh0, s, 0, 0, 0);
      s = __builtin_amdgcn_mfma_f32_16x16x32_bf16(qh1, kh1, s, 0, 0, 0);
      s = __builtin_amdgcn_mfma_f32_16x16x32_bf16(qh0, kl0, s, 0, 0, 0);
      s = __builtin_amdgcn_mfma_f32_16x16x32_bf16(qh1, kl1, s, 0, 0, 0);
      s = __builtin_amdgcn_mfma_f32_16x16x32_bf16(ql0, kh0, s, 0, 0, 0);
      s = __builtin_amdgcn_mfma_f32_16x16x32_bf16(ql1, kh1, s, 0, 0, 0);
      sacc[sub] = s;
    }
    __syncthreads();  // K tile fully consumed by all waves (V[vb] untouched)
    if (kt < 31) stage(kb + 64, (kt & 1) ^ 1);  // lands during threefry below

    // threefry + sigmoid sample -> swizzled Pm (0x3F80 / 0 bf16 mask)
    // u < p  <=>  m*(1+e) < 2^23, m = (float)((o0^o1)>>9), e = 2^(s*-log2e/8)
#pragma unroll
    for (int sub = 0; sub < 4; ++sub) {
      const int qP = sub * 2 + (c16 >> 3);
#pragma unroll
      for (int rr = 0; rr < 4; ++rr) {
        const uint32_t f = fb + (uint32_t)(rr * 2048) + (uint32_t)(kb + sub * 16);
        uint32_t o0, o1;
        threefry42(0u, f, o0, o1);
        const float m = (float)((o0 ^ o1) >> 9);
        const float e = __builtin_amdgcn_exp2f(sacc[sub][rr] * -0.18033688f);
        const int rP = w * 16 + quad * 4 + rr;
        const int addr = rP * 64 + (((qP + rP) & 7) * 8) + (c16 & 7);
        Pm[addr] = (fmaf(m, e, m) < 8388608.0f) ? 0x3F80u : 0u;
      }
    }

    // O += P.V — P rows wave-private (lgkmcnt orders write->read); V inline
    const int rp = w * 16 + c16;
    const short8 pa0 = *(const short8*)&Pm[rp * 64 + ((quad + rp) & 7) * 8];
    const short8 pa1 = *(const short8*)&Pm[rp * 64 + ((quad + 4 + rp) & 7) * 8];
#pragma unroll
    for (int sub = 0; sub < 4; ++sub) {
      const int rV = sub * 16 + c16;
      const short8 vv0 = *(const short8*)&Vs[vb + rV * 64 + ((quad + rV) & 7) * 8];
      const short8 vv1 = *(const short8*)&Vs[vb + rV * 64 + ((quad + 4 + rV) & 7) * 8];
      oacc[sub] = __builtin_amdgcn_mfma_f32_16x16x32_bf16(pa0, vv0, oacc[sub], 0, 0, 0);
      oacc[sub] = __builtin_amdgcn_mfma_f32_16x16x32_bf16(pa1, vv1, oacc[sub], 0, 0, 0);
    }
  }

  // epilogue: AO[b*2048+s][h*64+d] bf16; C-layout row=quad*4+r (q), col=c16 (d)
  const int b = bh >> 4, hh = bh & 15;
#pragma unroll
  for (int sub = 0; sub < 4; ++sub)
#pragma unroll
    for (int r = 0; r < 4; ++r) {
      const int srow = b * 2048 + q0 + w * 16 + quad * 4 + r;
      AO[(size_t)srow * 1024 + hh * 64 + sub * 16 + c16] = bf16_rne(oacc[sub][r]);
    }
}

// ---------------- kernel 3: output projection, bf16 MFMA ----------------
__global__ __launch_bounds__(256) void k_out(
    const unsigned short* __restrict__ A, const unsigned short* __restrict__ Bw,
    const float* __restrict__ out_b, float* __restrict__ out) {
  __shared__ unsigned short As[128 * 32], Bs[128 * 32];
  const int tid = threadIdx.x;
  const int lane = tid & 63, wid = tid >> 6;
  const int wm = wid >> 1, wn = wid & 1;
  const int bn = blockIdx.x, bm = blockIdx.y;
  const int quad = lane >> 4, c16 = lane & 15;
  const int ldrow = lane >> 2;
  const int ldk = (lane & 3) * 8;

  f4 acc[4][4];
#pragma unroll
  for (int a = 0; a < 4; ++a)
#pragma unroll
    for (int b = 0; b < 4; ++b) { f4 z = {0.f, 0.f, 0.f, 0.f}; acc[a][b] = z; }

  for (int kt = 0; kt < 32; ++kt) {
    const int k0 = kt * 32;
    __syncthreads();
#pragma unroll
    for (int r = 0; r < 2; ++r) {
      const int c = wid + r * 4;
      const int grow = c * 16 + ldrow;
      const size_t ao = (size_t)(bm * 128 + grow) * 1024 + k0 + ldk;
      const size_t bo = (size_t)(bn * 128 + grow) * 1024 + k0 + ldk;
      const int lo = c * 512 + lane * 8;
      gl2lds16(A + ao, &As[lo]);
      gl2lds16(Bw + bo, &Bs[lo]);
    }
    __syncthreads();

    short8 af[4], bf[4];
#pragma unroll
    for (int t = 0; t < 4; ++t) {
      af[t] = *(const short8*)&As[(wm * 64 + t * 16 + c16) * 32 + quad * 8];
      bf[t] = *(const short8*)&Bs[(wn * 64 + t * 16 + c16) * 32 + quad * 8];
    }
#pragma unroll
    for (int tm = 0; tm < 4; ++tm)
#pragma unroll
      for (int tn = 0; tn < 4; ++tn)
        acc[tm][tn] = __builtin_amdgcn_mfma_f32_16x16x32_bf16(af[tm], bf[tn], acc[tm][tn], 0, 0, 0);
  }

#pragma unroll
  for (int tm = 0; tm < 4; ++tm) {
#pragma unroll
    for (int tn = 0; tn < 4; ++tn) {
      const int j = bn * 128 + wn * 64 + tn * 16 + c16;
      const float bias = out_b[j];
#pragma unroll
      for (int r = 0; r < 4; ++r) {
        const int i = bm * 128 + wm * 64 + tm * 16 + quad * 4 + r;
        out[(size_t)i * 1024 + j] = acc[tm][tn][r] + bias;
      }
    }
  }
}

extern "C" void kernel_launch(void* const* d_in, const int* in_sizes, int n_in,
                              void* d_out, int out_size, void* d_ws, size_t ws_size,
                              hipStream_t stream) {
  const float* x     = (const float*)d_in[0];
  const float* qkv_w = (const float*)d_in[3];
  const float* qkv_b = (const float*)d_in[4];
  const float* out_w = (const float*)d_in[5];
  const float* out_b = (const float*)d_in[6];
  float* out = (float*)d_out;

  // workspace carve (ushorts); AO aliases xh (xh dead after k_qkv)
  unsigned short* xh  = (unsigned short*)d_ws;        // 4194304
  unsigned short* xl  = xh + 4194304;                 // 4194304
  unsigned short* wh  = xl + 4194304;                 // 3145728
  unsigned short* wl  = wh + 3145728;                 // 3145728
  unsigned short* woh = wl + 3145728;                 // 1048576
  unsigned short* Vt  = woh + 1048576;                // 4194304
  unsigned short* Qh  = Vt + 4194304;                 // 4194304
  unsigned short* Ql  = Qh + 4194304;                 // 4194304
  unsigned short* Kh  = Ql + 4194304;                 // 4194304
  unsigned short* Kl  = Kh + 4194304;                 // 4194304
  unsigned short* AO  = xh;                           // alias

  k_split<<<8192, 256, 0, stream>>>(x, qkv_w, out_w, xh, xl, wh, wl, woh);
  k_qkv<<<dim3(24, 32), 256, 0, stream>>>(xh, xl, wh, wl, qkv_b, Qh, Ql, Kh, Kl, Vt);
  k_attn<<<dim3(32, 32), 256, 0, stream>>>(Qh, Ql, Kh, Kl, Vt, AO);
  k_out<<<dim3(8, 32), 256, 0, stream>>>(AO, woh, out_b, out);
}